// Round 1
// 2388.824 us; speedup vs baseline: 2.1854x; 2.1854x over previous
//
#include <hip/hip_runtime.h>

typedef __attribute__((ext_vector_type(8))) short   short8;
typedef __attribute__((ext_vector_type(4))) float   float4_;
typedef __attribute__((ext_vector_type(4))) unsigned int uint4_;

// ---------------- workspace layout (bytes) ----------------
#define WPACK_OFF   0
#define WPACK_BYTES 786432                    // 1024 rows x 384 k x 2B, A-frag packed
#define HBUF_OFF    786432
#define HBUF_BYTES  524288                    // 4 slots x 256 batch x 64 ull (256 n bf16)
#define BIAS_OFF    (HBUF_OFF + HBUF_BYTES)

#define SLOT_ULL 16384                        // ulls per step-slot (256 batch * 64)
#define SENT_ULL 0xFFFFFFFFFFFFFFFFull        // bf16 NaN x4 — unreachable for finite h

__device__ __forceinline__ unsigned short f2bf(float f) {
  unsigned int u = __float_as_uint(f);
  u += 0x7fffu + ((u >> 16) & 1u);            // round-to-nearest-even
  return (unsigned short)(u >> 16);
}

// Pack W = [W_hh | W_ih] into MFMA A-fragment order, bf16.
// frag idx = (((s4*4 + wv)*4 + g)*12 + kt)*64 + lane
// row = g*256 + s4*64 + wv*16 + (lane&15);  k = kt*32 + (lane>>4)*8 + j
__global__ void pack_w(const float* __restrict__ w_ih,
                       const float* __restrict__ w_hh,
                       unsigned short* __restrict__ wpack) {
  int idx = blockIdx.x * blockDim.x + threadIdx.x;
  if (idx >= 49152) return;
  int lane = idx & 63;
  int r1 = idx >> 6;
  int kt = r1 % 12;
  int r2 = r1 / 12;
  int g  = r2 & 3;          // gate
  int r3 = r2 >> 2;
  int wv = r3 & 3;          // wave (n-subtile)
  int s4 = r3 >> 2;         // n-slice 0..3
  int row = g * 256 + s4 * 64 + wv * 16 + (lane & 15);
  int q = lane >> 4;
  short8 o;
#pragma unroll
  for (int j = 0; j < 8; ++j) {
    int kk = kt * 32 + q * 8 + j;             // 0..383
    float v = (kt < 8) ? w_hh[row * 256 + kk]
                       : w_ih[row * 128 + (kk - 256)];
    o[j] = (short)f2bf(v);
  }
  *(short8*)(wpack + (size_t)idx * 8) = o;
}

// Fill hbuf: slot 0 = bf16(h0), slots 1..3 = sentinel. Also bias = b_ih+b_hh.
__global__ void init_hb(const float* __restrict__ h0,
                        const float* __restrict__ b_ih,
                        const float* __restrict__ b_hh,
                        unsigned long long* __restrict__ hbuf,
                        float* __restrict__ bias) {
  int idx = blockIdx.x * blockDim.x + threadIdx.x;
  if (idx < 16384) {                           // slot 0: seed h0 (4 bf16 per ull)
    unsigned long long v = 0;
#pragma unroll
    for (int e = 0; e < 4; ++e)
      v |= (unsigned long long)f2bf(h0[idx * 4 + e]) << (16 * e);
    hbuf[idx] = v;
  } else if (idx < 65536) {                    // slots 1..3: sentinel
    hbuf[idx] = SENT_ULL;
  } else if (idx < 66560) {
    int j = idx - 65536;
    bias[j] = b_ih[j] + b_hh[j];
  }
}

__device__ __forceinline__ float sigm_(float v) {
  return 1.f / (1.f + __expf(-v));
}
__device__ __forceinline__ float tanh_(float v) {
  return 1.f - 2.f / (__expf(2.f * v) + 1.f);  // robust at +-inf
}

// Grid 64: id = s4*16 + grp-ish; s4 = id>>4, grp = id&15 -> the 4 blocks of a
// group are ids {g, g+16, g+32, g+48} == same (id % 8) -> same XCD under the
// round-robin dispatch heuristic (perf-only assumption).
__global__ __launch_bounds__(256, 1) void lstm_main(
    const float* __restrict__ x, const float* __restrict__ c0,
    const unsigned short* __restrict__ wpack, const float* __restrict__ bias,
    unsigned long long* hbuf, float* __restrict__ out) {

  const int tid  = threadIdx.x;
  const int wv   = tid >> 6;       // wave == n-subtile 0..3 (owns all 4 gates)
  const int lane = tid & 63;
  const int q    = lane >> 4;
  const int bl   = lane & 15;

  const int id  = blockIdx.x;
  const int s4  = id >> 4;                  // n-slice 0..3 (64 n each)
  const int grp = id & 15;                  // batch group 0..15

  const int bg = grp * 16 + bl;             // my batch (B-frag column)

  // ---- W fragments in VGPRs: 4 gates x 12 ktiles = 48 frags (192 regs) ----
  short8 wf[48];
  {
    const unsigned short* base =
        wpack + ((size_t)((s4 * 4 + wv) * 48) * 64 + lane) * 8;
#pragma unroll
    for (int f = 0; f < 48; ++f)
      wf[f] = *(const short8*)(base + (size_t)f * 512);
  }
#pragma unroll
  for (int f = 0; f < 48; ++f)
    asm volatile("" : "+v"(wf[f]));          // 192 pinned + ~110 live < 512: safe

  // bias per gate (acc init); C-rows of my tile = wv*16 + q*4 + r
  float4_ bia[4];
#pragma unroll
  for (int g = 0; g < 4; ++g)
    bia[g] = *(const float4_*)(bias + g * 256 + s4 * 64 + wv * 16 + q * 4);

  // c state: this thread owns n = s4*64 + wv*16 + q*4 + r, batch bl
  float4_ cst = *(const float4_*)(c0 + (size_t)bg * 256 + s4 * 64 + wv * 16 + q * 4);

  // my produced h chunk (4 bf16 = 1 ull), and its hbuf index
  const size_t my_ull = (size_t)bg * 64 + s4 * 16 + wv * 4 + q;
  unsigned long long hull = hbuf[my_ull];   // slot 0 = bf16(h0) self chunk

  // x prefetch for t=0: k = wv*32 + q*8 + [0,8)
  const float* xb = x + (size_t)bg * 131072 + wv * 32 + q * 8;
  float4_ xr0 = *(const float4_*)(xb);
  float4_ xr1 = *(const float4_*)(xb + 4);

  // shared frag buffer: ktiles 0..7 = h, 8..11 = x. 16B/lane contiguous ->
  // conflict-free ds_read_b128/ds_write_b128.
  __shared__ uint4_ hbf[12][64];

  float4_ hf;

#pragma unroll 1
  for (int t = 0; t < 1024; ++t) {
    // ---------- phase A: publish x-frag + own h chunk; poll foreign h ----------
    {
      short8 xf;
#pragma unroll
      for (int e = 0; e < 4; ++e) {
        xf[e]     = (short)f2bf(xr0[e]);
        xf[e + 4] = (short)f2bf(xr1[e]);
      }
      *(short8*)&hbf[8 + wv][lane] = xf;
    }
    // self h short-circuit: own slice never round-trips through MALL.
    // my 4 values = j in [4*(q&1),4*(q&1)+4) of frag lane (2*(wv&1)+(q>>1))*16+bl
    // of ktile 2*s4 + (wv>>1).
    ((unsigned long long*)&hbf[2 * s4 + (wv >> 1)]
                              [(2 * (wv & 1) + (q >> 1)) * 16 + bl])[q & 1] = hull;

    if (wv != s4) {   // 3 waves poll the 6 foreign ktiles {2wv, 2wv+1}
      unsigned long long* hb =
          hbuf + (size_t)(t & 3) * SLOT_ULL + (size_t)bg * 64 + wv * 16 + q * 2;
      unsigned long long p0, p1, p2, p3;
      for (;;) {
        p0 = __hip_atomic_load(hb,     __ATOMIC_RELAXED, __HIP_MEMORY_SCOPE_AGENT);
        p1 = __hip_atomic_load(hb + 1, __ATOMIC_RELAXED, __HIP_MEMORY_SCOPE_AGENT);
        p2 = __hip_atomic_load(hb + 8, __ATOMIC_RELAXED, __HIP_MEMORY_SCOPE_AGENT);
        p3 = __hip_atomic_load(hb + 9, __ATOMIC_RELAXED, __HIP_MEMORY_SCOPE_AGENT);
        // each ull is stored atomically by one producer thread: low16 test suffices
        bool ok = ((unsigned short)p0 != 0xFFFFu) & ((unsigned short)p1 != 0xFFFFu)
                & ((unsigned short)p2 != 0xFFFFu) & ((unsigned short)p3 != 0xFFFFu);
        if (__all(ok)) break;
        __builtin_amdgcn_s_sleep(1);
      }
      asm volatile("" ::: "memory");   // nothing hoists above the poll
      union { unsigned long long u[2]; uint4_ v; } u0, u1;
      u0.u[0] = p0; u0.u[1] = p1;
      u1.u[0] = p2; u1.u[1] = p3;
      hbf[2 * wv][lane]     = u0.v;
      hbf[2 * wv + 1][lane] = u1.v;
    }
    __syncthreads();                         // bar1: hbf complete

    // ---------- phase B: prefetch x(t+1); 48 MFMAs ----------
    {
      int tn = (t < 1023) ? (t + 1) : 1023;
      xr0 = *(const float4_*)(xb + (size_t)tn * 128);
      xr1 = *(const float4_*)(xb + (size_t)tn * 128 + 4);
    }

    float4_ acc[4];
#pragma unroll
    for (int g = 0; g < 4; ++g) acc[g] = bia[g];

#pragma unroll
    for (int kt = 0; kt < 12; ++kt) {
      short8 bf = *(const short8*)&hbf[kt][lane];
#pragma unroll
      for (int g = 0; g < 4; ++g)
        acc[g] = __builtin_amdgcn_mfma_f32_16x16x32_bf16(wf[g * 12 + kt], bf, acc[g], 0, 0, 0);
    }

    // ---------- phase C: reset old slot; in-register combine; publish h ----------
    // Safe: detecting h_t (bar1) implies every block produced h_t, hence every
    // block consumed h_{t-1}; reset->later-store visibility ordered by the
    // vmcnt drains of the intervening iterations. 4 slots > 3 required.
    if (t > 0) {
      unsigned long long* rp =
          hbuf + (size_t)((t - 1) & 3) * SLOT_ULL + my_ull;
      __hip_atomic_store(rp, SENT_ULL, __ATOMIC_RELAXED, __HIP_MEMORY_SCOPE_AGENT);
    }
    {
      unsigned long long nh = 0;
#pragma unroll
      for (int r = 0; r < 4; ++r) {
        float iv = sigm_(acc[0][r]);
        float fv = sigm_(acc[1][r]);
        float gv = tanh_(acc[2][r]);
        float ov = sigm_(acc[3][r]);
        float cv = fv * cst[r] + iv * gv;
        cst[r] = cv;
        float hv = ov * tanh_(cv);
        hf[r] = hv;
        nh |= (unsigned long long)f2bf(hv) << (16 * r);
      }
      hull = nh;
      unsigned long long* dst =
          hbuf + (size_t)((t + 1) & 3) * SLOT_ULL + my_ull;
      __hip_atomic_store(dst, hull, __ATOMIC_RELAXED, __HIP_MEMORY_SCOPE_AGENT);
    }
    __syncthreads();                         // bar2: hbf reads done before next A writes
  }

  // final h (fp32) -> d_out [1,B,H]
  *(float4_*)(out + (size_t)bg * 256 + s4 * 64 + wv * 16 + q * 4) = hf;
}

extern "C" void kernel_launch(void* const* d_in, const int* in_sizes, int n_in,
                              void* d_out, int out_size, void* d_ws, size_t ws_size,
                              hipStream_t stream) {
  (void)in_sizes; (void)n_in; (void)out_size; (void)ws_size;
  const float* x    = (const float*)d_in[0];
  const float* h0   = (const float*)d_in[1];
  const float* c0   = (const float*)d_in[2];
  const float* w_ih = (const float*)d_in[3];
  const float* w_hh = (const float*)d_in[4];
  const float* b_ih = (const float*)d_in[5];
  const float* b_hh = (const float*)d_in[6];

  char* ws = (char*)d_ws;
  unsigned short*     wpack = (unsigned short*)(ws + WPACK_OFF);
  unsigned long long* hbuf  = (unsigned long long*)(ws + HBUF_OFF);
  float*              bias  = (float*)(ws + BIAS_OFF);

  pack_w<<<192, 256, 0, stream>>>(w_ih, w_hh, wpack);
  init_hb<<<260, 256, 0, stream>>>(h0, b_ih, b_hh, hbuf, bias);
  lstm_main<<<64, 256, 0, stream>>>(x, c0, wpack, bias, hbuf, (float*)d_out);
}